// Round 1
// baseline (92.117 us; speedup 1.0000x reference)
//
#include <hip/hip_runtime.h>

typedef short s16x8 __attribute__((ext_vector_type(8)));
typedef float f32x4 __attribute__((ext_vector_type(4)));
typedef unsigned short us4 __attribute__((ext_vector_type(4)));

static __device__ __forceinline__ unsigned short f2bf(float f) {
  unsigned u = __builtin_bit_cast(unsigned, f);
  u += 0x7FFFu + ((u >> 16) & 1u);
  return (unsigned short)(u >> 16);
}

#define MFMA16(a, b, c) __builtin_amdgcn_mfma_f32_16x16x32_bf16((a), (b), (c), 0, 0, 0)

// ---------------------------------------------------------------------------
// Projection: out = x @ W^T for q,k,v.  x:[8,2048,768] f32, W:[64,768] f32.
// q,k stored row-major bf16 [8][2048][64] (q pre-scaled by 1/8).
// v stored transposed bf16 vt[8][64][2048] so attention B-frags are contiguous.
// grid = 3*256 blocks (t = bid>>8), 256 threads (4 waves), 64 s-rows per block.
// ---------------------------------------------------------------------------
__global__ __launch_bounds__(256) void proj_kernel(
    const float* __restrict__ Xq, const float* __restrict__ Xk, const float* __restrict__ Xv,
    const float* __restrict__ Wq, const float* __restrict__ Wk, const float* __restrict__ Wv,
    unsigned short* __restrict__ qk_out,  // [2][8][2048][64]
    unsigned short* __restrict__ vt_out)  // [8][64][2048]
{
  __shared__ __align__(16) unsigned short xs[64][72];
  __shared__ __align__(16) unsigned short ws[64][72];

  const int bid = blockIdx.x;
  const int t = bid >> 8;          // 0=q 1=k 2=v
  const int rb = bid & 255;
  const int b = rb >> 5;
  const int stile = rb & 31;
  const float* X = (t == 0) ? Xq : (t == 1) ? Xk : Xv;
  const float* W = (t == 0) ? Wq : (t == 1) ? Wk : Wv;

  const int tid = threadIdx.x;
  const int wv = tid >> 6;
  const int lane = tid & 63;
  const int j = lane & 15;
  const int g = lane >> 4;

  f32x4 acc[4];
#pragma unroll
  for (int i = 0; i < 4; ++i) acc[i] = {0.f, 0.f, 0.f, 0.f};

  const size_t xrow0 = (size_t)b * 2048 + (size_t)stile * 64;

  for (int kc = 0; kc < 768; kc += 64) {
    // stage x-tile [64][64] and W-tile [64][64] as bf16 (coalesced float4 reads)
#pragma unroll
    for (int p = 0; p < 4; ++p) {
      int lin = p * 256 + tid;   // 0..1023
      int row = lin >> 4;        // 0..63
      int seg = lin & 15;        // 16 float4 per row
      float4 xv = *(const float4*)(X + (xrow0 + row) * 768 + kc + seg * 4);
      us4 px; px.x = f2bf(xv.x); px.y = f2bf(xv.y); px.z = f2bf(xv.z); px.w = f2bf(xv.w);
      *(us4*)&xs[row][seg * 4] = px;
      float4 wv4 = *(const float4*)(W + (size_t)row * 768 + kc + seg * 4);
      us4 pw; pw.x = f2bf(wv4.x); pw.y = f2bf(wv4.y); pw.z = f2bf(wv4.z); pw.w = f2bf(wv4.w);
      *(us4*)&ws[row][seg * 4] = pw;
    }
    __syncthreads();
    s16x8 a0 = *(const s16x8*)&xs[wv * 16 + j][g * 8];
    s16x8 a1 = *(const s16x8*)&xs[wv * 16 + j][32 + g * 8];
#pragma unroll
    for (int ct = 0; ct < 4; ++ct) {
      s16x8 b0 = *(const s16x8*)&ws[ct * 16 + j][g * 8];
      s16x8 b1 = *(const s16x8*)&ws[ct * 16 + j][32 + g * 8];
      acc[ct] = MFMA16(a0, b0, acc[ct]);
      acc[ct] = MFMA16(a1, b1, acc[ct]);
    }
    __syncthreads();
  }

  if (t < 2) {
    const float s = (t == 0) ? 0.125f : 1.0f;  // fold 1/sqrt(64) into q
    unsigned short* out = qk_out + (size_t)t * (8u * 2048u * 64u) + (xrow0 + (size_t)wv * 16) * 64;
#pragma unroll
    for (int ct = 0; ct < 4; ++ct)
#pragma unroll
      for (int r = 0; r < 4; ++r)
        out[(g * 4 + r) * 64 + ct * 16 + j] = f2bf(acc[ct][r] * s);
  } else {
    // transposed store: rows g*4+r are contiguous in s -> packed 8B stores
#pragma unroll
    for (int ct = 0; ct < 4; ++ct) {
      int d = ct * 16 + j;
      us4 pk;
      pk.x = f2bf(acc[ct][0]); pk.y = f2bf(acc[ct][1]);
      pk.z = f2bf(acc[ct][2]); pk.w = f2bf(acc[ct][3]);
      *(us4*)(vt_out + ((size_t)b * 64 + d) * 2048 + stile * 64 + wv * 16 + g * 4) = pk;
    }
  }
}

// ---------------------------------------------------------------------------
// Flash attention: grid 256 blocks (XCD-chunked so batch==XCD), 4 waves/block,
// 16 q-rows per wave, KT=64 per iteration, 32 iterations.
// Computes S^T = K·Q^T (D-layout puts a q-row's scores on 4 lanes -> 2 shfl
// reduce), online softmax, P staged through per-wave LDS, O = P·V with Vt.
// ---------------------------------------------------------------------------
__global__ __launch_bounds__(256) void attn_kernel(
    const unsigned short* __restrict__ qg,  // [8][2048][64] (pre-scaled)
    const unsigned short* __restrict__ kg,  // [8][2048][64]
    const unsigned short* __restrict__ vt,  // [8][64][2048]
    float* __restrict__ out)                // [8][2048][64] f32
{
  __shared__ __align__(16) unsigned short p_lds[4][16][72];
  const int tid = threadIdx.x;
  const int wv = tid >> 6;
  const int lane = tid & 63;
  const int j = lane & 15;
  const int g = lane >> 4;

  const int bid0 = blockIdx.x;
  const int bid = (bid0 & 7) * 32 + (bid0 >> 3);  // bijective XCD swizzle (256 = 8*32)
  const int b = bid >> 5;
  const int qtile = bid & 31;
  const int qbase = qtile * 64 + wv * 16;

  const unsigned short* qp = qg + (((size_t)b * 2048) + qbase) * 64;
  s16x8 q0 = *(const s16x8*)(qp + j * 64 + g * 8);
  s16x8 q1 = *(const s16x8*)(qp + j * 64 + 32 + g * 8);

  f32x4 o[4];
#pragma unroll
  for (int i = 0; i < 4; ++i) o[i] = {0.f, 0.f, 0.f, 0.f};
  float m = -1e30f, l = 0.f;

  const unsigned short* kb = kg + (size_t)b * 2048 * 64;
  const unsigned short* vb = vt + (size_t)b * 64 * 2048;

  for (int kt = 0; kt < 32; ++kt) {
    const int kbase = kt * 64;
    // S^T tiles: A = K frag, B = Q frag (identical load patterns)
    f32x4 st[4];
#pragma unroll
    for (int ct = 0; ct < 4; ++ct) {
      const unsigned short* kp = kb + (size_t)(kbase + ct * 16 + j) * 64;
      s16x8 k0 = *(const s16x8*)(kp + g * 8);
      s16x8 k1 = *(const s16x8*)(kp + 32 + g * 8);
      f32x4 z = {0.f, 0.f, 0.f, 0.f};
      z = MFMA16(k0, q0, z);
      z = MFMA16(k1, q1, z);
      st[ct] = z;  // st[ct][r] = S[q=j][k = kbase + ct*16 + g*4 + r]
    }
    // row max: 15 in-lane + 2 shfl (lanes j, j+16, j+32, j+48 share q-row j)
    float cmax = -1e30f;
#pragma unroll
    for (int ct = 0; ct < 4; ++ct)
#pragma unroll
      for (int r = 0; r < 4; ++r) cmax = fmaxf(cmax, st[ct][r]);
    cmax = fmaxf(cmax, __shfl_xor(cmax, 16));
    cmax = fmaxf(cmax, __shfl_xor(cmax, 32));
    const float mnew = fmaxf(m, cmax);
    const float alpha = __expf(m - mnew);
    m = mnew;
    float rs = 0.f;
#pragma unroll
    for (int ct = 0; ct < 4; ++ct) {
      float p0 = __expf(st[ct][0] - mnew);
      float p1 = __expf(st[ct][1] - mnew);
      float p2 = __expf(st[ct][2] - mnew);
      float p3 = __expf(st[ct][3] - mnew);
      rs += (p0 + p1) + (p2 + p3);
      us4 pk; pk.x = f2bf(p0); pk.y = f2bf(p1); pk.z = f2bf(p2); pk.w = f2bf(p3);
      *(us4*)&p_lds[wv][j][ct * 16 + g * 4] = pk;  // P[q=j][k-local] packed
    }
    rs += __shfl_xor(rs, 16);
    rs += __shfl_xor(rs, 32);
    l = l * alpha + rs;
    // rescale O (O rows are g*4+r; alpha lives on lane with j==row)
#pragma unroll
    for (int r = 0; r < 4; ++r) {
      float a_r = __shfl(alpha, g * 4 + r);
#pragma unroll
      for (int dt = 0; dt < 4; ++dt) o[dt][r] *= a_r;
    }
    // PV: A = P from LDS (row q = lane&15), B = Vt contiguous frags
    s16x8 pa0 = *(const s16x8*)&p_lds[wv][j][g * 8];
    s16x8 pa1 = *(const s16x8*)&p_lds[wv][j][32 + g * 8];
#pragma unroll
    for (int dt = 0; dt < 4; ++dt) {
      const unsigned short* vp = vb + (size_t)(dt * 16 + j) * 2048 + kbase;
      s16x8 v0 = *(const s16x8*)(vp + g * 8);
      s16x8 v1 = *(const s16x8*)(vp + 32 + g * 8);
      o[dt] = MFMA16(pa0, v0, o[dt]);
      o[dt] = MFMA16(pa1, v1, o[dt]);
    }
  }
  // epilogue: O[q = g*4+r][d = dt*16+j] / l_row
#pragma unroll
  for (int r = 0; r < 4; ++r) {
    float l_r = __shfl(l, g * 4 + r);
    float inv = 1.0f / l_r;
    const int row = qbase + g * 4 + r;
    float* op = out + ((size_t)b * 2048 + row) * 64;
#pragma unroll
    for (int dt = 0; dt < 4; ++dt) op[dt * 16 + j] = o[dt][r] * inv;
  }
}

extern "C" void kernel_launch(void* const* d_in, const int* in_sizes, int n_in,
                              void* d_out, int out_size, void* d_ws, size_t ws_size,
                              hipStream_t stream) {
  const float* query = (const float*)d_in[0];
  const float* key_  = (const float*)d_in[1];
  const float* value = (const float*)d_in[2];
  const float* Wq = (const float*)d_in[3];
  const float* Wk = (const float*)d_in[4];
  const float* Wv = (const float*)d_in[5];

  unsigned short* qk = (unsigned short*)d_ws;       // q: 1M elems, k: next 1M
  unsigned short* vt = qk + 2u * 1048576u;          // 1M elems
  float* outp = (float*)d_out;

  hipLaunchKernelGGL(proj_kernel, dim3(768), dim3(256), 0, stream,
                     query, key_, value, Wq, Wk, Wv, qk, vt);
  hipLaunchKernelGGL(attn_kernel, dim3(256), dim3(256), 0, stream,
                     qk, qk + 1048576u, vt, outp);
}

// Round 2
// 90.416 us; speedup vs baseline: 1.0188x; 1.0188x over previous
//
#include <hip/hip_runtime.h>

typedef short s16x8 __attribute__((ext_vector_type(8)));
typedef float f32x4 __attribute__((ext_vector_type(4)));
typedef unsigned short us4 __attribute__((ext_vector_type(4)));

static __device__ __forceinline__ unsigned short f2bf(float f) {
  unsigned u = __builtin_bit_cast(unsigned, f);
  u += 0x7FFFu + ((u >> 16) & 1u);
  return (unsigned short)(u >> 16);
}

#define MFMA16(a, b, c) __builtin_amdgcn_mfma_f32_16x16x32_bf16((a), (b), (c), 0, 0, 0)

// ---------------------------------------------------------------------------
// Projection: out = x @ W^T for q,k,v.  x:[8,2048,768] f32, W:[64,768] f32.
// q,k stored row-major bf16 [8][2048][64] (q pre-scaled by 1/8).
// v stored transposed bf16 vt[8][64][2048] so attention B-frags are contiguous.
// grid = 3*256 blocks (t = bid>>8), 256 threads (4 waves), 64 s-rows per block.
// ---------------------------------------------------------------------------
__global__ __launch_bounds__(256) void proj_kernel(
    const float* __restrict__ Xq, const float* __restrict__ Xk, const float* __restrict__ Xv,
    const float* __restrict__ Wq, const float* __restrict__ Wk, const float* __restrict__ Wv,
    unsigned short* __restrict__ qk_out,  // [2][8][2048][64]
    unsigned short* __restrict__ vt_out)  // [8][64][2048]
{
  __shared__ __align__(16) unsigned short xs[64][72];
  __shared__ __align__(16) unsigned short ws[64][72];

  const int bid = blockIdx.x;
  const int t = bid >> 8;          // 0=q 1=k 2=v
  const int rb = bid & 255;
  const int b = rb >> 5;
  const int stile = rb & 31;
  const float* X = (t == 0) ? Xq : (t == 1) ? Xk : Xv;
  const float* W = (t == 0) ? Wq : (t == 1) ? Wk : Wv;

  const int tid = threadIdx.x;
  const int wv = tid >> 6;
  const int lane = tid & 63;
  const int j = lane & 15;
  const int g = lane >> 4;

  f32x4 acc[4];
#pragma unroll
  for (int i = 0; i < 4; ++i) acc[i] = {0.f, 0.f, 0.f, 0.f};

  const size_t xrow0 = (size_t)b * 2048 + (size_t)stile * 64;

  for (int kc = 0; kc < 768; kc += 64) {
#pragma unroll
    for (int p = 0; p < 4; ++p) {
      int lin = p * 256 + tid;   // 0..1023
      int row = lin >> 4;        // 0..63
      int seg = lin & 15;        // 16 float4 per row
      float4 xv = *(const float4*)(X + (xrow0 + row) * 768 + kc + seg * 4);
      us4 px; px.x = f2bf(xv.x); px.y = f2bf(xv.y); px.z = f2bf(xv.z); px.w = f2bf(xv.w);
      *(us4*)&xs[row][seg * 4] = px;
      float4 wv4 = *(const float4*)(W + (size_t)row * 768 + kc + seg * 4);
      us4 pw; pw.x = f2bf(wv4.x); pw.y = f2bf(wv4.y); pw.z = f2bf(wv4.z); pw.w = f2bf(wv4.w);
      *(us4*)&ws[row][seg * 4] = pw;
    }
    __syncthreads();
    s16x8 a0 = *(const s16x8*)&xs[wv * 16 + j][g * 8];
    s16x8 a1 = *(const s16x8*)&xs[wv * 16 + j][32 + g * 8];
#pragma unroll
    for (int ct = 0; ct < 4; ++ct) {
      s16x8 b0 = *(const s16x8*)&ws[ct * 16 + j][g * 8];
      s16x8 b1 = *(const s16x8*)&ws[ct * 16 + j][32 + g * 8];
      acc[ct] = MFMA16(a0, b0, acc[ct]);
      acc[ct] = MFMA16(a1, b1, acc[ct]);
    }
    __syncthreads();
  }

  if (t < 2) {
    const float s = (t == 0) ? 0.125f : 1.0f;  // fold 1/sqrt(64) into q
    unsigned short* out = qk_out + (size_t)t * (8u * 2048u * 64u) + (xrow0 + (size_t)wv * 16) * 64;
#pragma unroll
    for (int ct = 0; ct < 4; ++ct)
#pragma unroll
      for (int r = 0; r < 4; ++r)
        out[(g * 4 + r) * 64 + ct * 16 + j] = f2bf(acc[ct][r] * s);
  } else {
#pragma unroll
    for (int ct = 0; ct < 4; ++ct) {
      int d = ct * 16 + j;
      us4 pk;
      pk.x = f2bf(acc[ct][0]); pk.y = f2bf(acc[ct][1]);
      pk.z = f2bf(acc[ct][2]); pk.w = f2bf(acc[ct][3]);
      *(us4*)(vt_out + ((size_t)b * 64 + d) * 2048 + stile * 64 + wv * 16 + g * 4) = pk;
    }
  }
}

// ---------------------------------------------------------------------------
// Flash attention, in-block split-K. grid = 1024 blocks (XCD-chunked so
// batch==XCD), 4 waves/block. Block owns 16 q-rows; wave wv processes KV
// chunk [wv*512, wv*512+512) in 8 iterations of KT=64, keeping partial
// (o, m, l). Partials merged through LDS:
//   out = sum_c exp(m_c - M) * o_c / sum_c exp(m_c - M) * l_c.
// ---------------------------------------------------------------------------
__global__ __launch_bounds__(256) void attn_kernel(
    const unsigned short* __restrict__ qg,  // [8][2048][64] (pre-scaled)
    const unsigned short* __restrict__ kg,  // [8][2048][64]
    const unsigned short* __restrict__ vt,  // [8][64][2048]
    float* __restrict__ out)                // [8][2048][64] f32
{
  __shared__ __align__(16) unsigned short p_lds[4][16][72];
  __shared__ __align__(16) float comb[4][16][68];
  __shared__ float mls[4][16];
  __shared__ float lls[4][16];

  const int tid = threadIdx.x;
  const int wv = tid >> 6;
  const int lane = tid & 63;
  const int j = lane & 15;
  const int g = lane >> 4;

  const int bid0 = blockIdx.x;
  const int bid = (bid0 & 7) * 128 + (bid0 >> 3);  // bijective XCD swizzle (1024 = 8*128)
  const int b = bid >> 7;
  const int qtile = bid & 127;
  const int qbase = qtile * 16;

  const unsigned short* qp = qg + (((size_t)b * 2048) + qbase) * 64;
  s16x8 q0 = *(const s16x8*)(qp + j * 64 + g * 8);
  s16x8 q1 = *(const s16x8*)(qp + j * 64 + 32 + g * 8);

  f32x4 o[4];
#pragma unroll
  for (int i = 0; i < 4; ++i) o[i] = {0.f, 0.f, 0.f, 0.f};
  float m = -1e30f, l = 0.f;

  const unsigned short* kb = kg + (size_t)b * 2048 * 64;
  const unsigned short* vb = vt + (size_t)b * 64 * 2048;
  const int kv0 = wv * 512;  // this wave's KV chunk

  for (int kt = 0; kt < 8; ++kt) {
    const int kbase = kv0 + kt * 64;
    // S^T tiles: A = K frag, B = Q frag (identical load patterns)
    f32x4 st[4];
#pragma unroll
    for (int ct = 0; ct < 4; ++ct) {
      const unsigned short* kp = kb + (size_t)(kbase + ct * 16 + j) * 64;
      s16x8 k0 = *(const s16x8*)(kp + g * 8);
      s16x8 k1 = *(const s16x8*)(kp + 32 + g * 8);
      f32x4 z = {0.f, 0.f, 0.f, 0.f};
      z = MFMA16(k0, q0, z);
      z = MFMA16(k1, q1, z);
      st[ct] = z;  // st[ct][r] = S[q=j][k = kbase + ct*16 + g*4 + r]
    }
    // row max: in-lane + 2 shfl (lanes j, j+16, j+32, j+48 share q-row j)
    float cmax = -1e30f;
#pragma unroll
    for (int ct = 0; ct < 4; ++ct)
#pragma unroll
      for (int r = 0; r < 4; ++r) cmax = fmaxf(cmax, st[ct][r]);
    cmax = fmaxf(cmax, __shfl_xor(cmax, 16));
    cmax = fmaxf(cmax, __shfl_xor(cmax, 32));
    const float mnew = fmaxf(m, cmax);
    const float alpha = __expf(m - mnew);
    m = mnew;
    float rs = 0.f;
#pragma unroll
    for (int ct = 0; ct < 4; ++ct) {
      float p0 = __expf(st[ct][0] - mnew);
      float p1 = __expf(st[ct][1] - mnew);
      float p2 = __expf(st[ct][2] - mnew);
      float p3 = __expf(st[ct][3] - mnew);
      rs += (p0 + p1) + (p2 + p3);
      us4 pk; pk.x = f2bf(p0); pk.y = f2bf(p1); pk.z = f2bf(p2); pk.w = f2bf(p3);
      *(us4*)&p_lds[wv][j][ct * 16 + g * 4] = pk;  // P[q=j][k-local]
    }
    rs += __shfl_xor(rs, 16);
    rs += __shfl_xor(rs, 32);
    l = l * alpha + rs;
    // rescale O (O rows are g*4+r; alpha lives on lane with j==row)
#pragma unroll
    for (int r = 0; r < 4; ++r) {
      float a_r = __shfl(alpha, g * 4 + r);
#pragma unroll
      for (int dt = 0; dt < 4; ++dt) o[dt][r] *= a_r;
    }
    // PV: A = P from LDS (row q = lane&15), B = Vt contiguous frags
    s16x8 pa0 = *(const s16x8*)&p_lds[wv][j][g * 8];
    s16x8 pa1 = *(const s16x8*)&p_lds[wv][j][32 + g * 8];
#pragma unroll
    for (int dt = 0; dt < 4; ++dt) {
      const unsigned short* vp = vb + (size_t)(dt * 16 + j) * 2048 + kbase;
      s16x8 v0 = *(const s16x8*)(vp + g * 8);
      s16x8 v1 = *(const s16x8*)(vp + 32 + g * 8);
      o[dt] = MFMA16(pa0, v0, o[dt]);
      o[dt] = MFMA16(pa1, v1, o[dt]);
    }
  }

  // ---- write partials to LDS: o rows q = g*4+r, cols d = dt*16+j ----
#pragma unroll
  for (int dt = 0; dt < 4; ++dt)
#pragma unroll
    for (int r = 0; r < 4; ++r)
      comb[wv][g * 4 + r][dt * 16 + j] = o[dt][r];
  if (g == 0) { mls[wv][j] = m; lls[wv][j] = l; }
  __syncthreads();

  // ---- combine: wave wv merges rows wv*4 .. wv*4+3; lane = d index ----
#pragma unroll
  for (int rr = 0; rr < 4; ++rr) {
    const int row = wv * 4 + rr;
    float m0 = mls[0][row], m1 = mls[1][row], m2 = mls[2][row], m3 = mls[3][row];
    float M = fmaxf(fmaxf(m0, m1), fmaxf(m2, m3));
    float w0 = __expf(m0 - M), w1 = __expf(m1 - M);
    float w2 = __expf(m2 - M), w3 = __expf(m3 - M);
    float acc = comb[0][row][lane] * w0 + comb[1][row][lane] * w1 +
                comb[2][row][lane] * w2 + comb[3][row][lane] * w3;
    float lt = lls[0][row] * w0 + lls[1][row] * w1 +
               lls[2][row] * w2 + lls[3][row] * w3;
    out[(((size_t)b * 2048) + qbase + row) * 64 + lane] = acc / lt;
  }
}

extern "C" void kernel_launch(void* const* d_in, const int* in_sizes, int n_in,
                              void* d_out, int out_size, void* d_ws, size_t ws_size,
                              hipStream_t stream) {
  const float* query = (const float*)d_in[0];
  const float* key_  = (const float*)d_in[1];
  const float* value = (const float*)d_in[2];
  const float* Wq = (const float*)d_in[3];
  const float* Wk = (const float*)d_in[4];
  const float* Wv = (const float*)d_in[5];

  unsigned short* qk = (unsigned short*)d_ws;       // q: 1M elems, k: next 1M
  unsigned short* vt = qk + 2u * 1048576u;          // 1M elems
  float* outp = (float*)d_out;

  hipLaunchKernelGGL(proj_kernel, dim3(768), dim3(256), 0, stream,
                     query, key_, value, Wq, Wk, Wv, qk, vt);
  hipLaunchKernelGGL(attn_kernel, dim3(1024), dim3(256), 0, stream,
                     qk, qk + 1048576u, vt, outp);
}

// Round 4
// 52.796 us; speedup vs baseline: 1.7448x; 1.7126x over previous
//
#include <hip/hip_runtime.h>

typedef short s16x8 __attribute__((ext_vector_type(8)));
typedef float f32x4 __attribute__((ext_vector_type(4)));
typedef unsigned short us4 __attribute__((ext_vector_type(4)));

static __device__ __forceinline__ unsigned short f2bf(float f) {
  unsigned u = __builtin_bit_cast(unsigned, f);
  u += 0x7FFFu + ((u >> 16) & 1u);
  return (unsigned short)(u >> 16);
}

#define MFMA16(a, b, c) __builtin_amdgcn_mfma_f32_16x16x32_bf16((a), (b), (c), 0, 0, 0)

// ---------------------------------------------------------------------------
// Projection: out = x @ W^T for q,k,v.  x:[8,2048,768] f32, W:[64,768] f32.
// q stored row-major bf16 [8][2048][64] (pre-scaled by 1/8 -- DO NOT DROP).
// K stored FRAGMENT-MAJOR per 16-row chunk c = b*128 + s/16:
//   addr16 = c*1024 + h*512 + lane*8 + e  holds K[c*16 + (lane&15)][h*32 + (lane>>4)*8 + e]
//   -> attention A-frag load is base + lane*16B, fully coalesced.
// V stored FRAGMENT-MAJOR per 64-row chunk c = b*32 + s/64:
//   addr16 = c*4096 + dt*1024 + h*512 + lane*8 + e
//   holds V[c*64 + h*32 + (lane>>4)*8 + e][dt*16 + (lane&15)]
//   -> attention B-frag load is base + lane*16B.
// Fragment scatter goes through LDS so global writes stay coalesced.
// ---------------------------------------------------------------------------
__global__ __launch_bounds__(256) void proj_kernel(
    const float* __restrict__ Xq, const float* __restrict__ Xk, const float* __restrict__ Xv,
    const float* __restrict__ Wq, const float* __restrict__ Wk, const float* __restrict__ Wv,
    unsigned short* __restrict__ q_out,   // [8][2048][64] row-major
    unsigned short* __restrict__ kf_out,  // [8*128][1024] frag-major
    unsigned short* __restrict__ vf_out)  // [8*32][4096] frag-major
{
  __shared__ __align__(16) unsigned short xs[64][72];
  __shared__ __align__(16) unsigned short ws[64][72];

  const int bid = blockIdx.x;
  const int t = bid >> 8;          // 0=q 1=k 2=v
  const int rb = bid & 255;
  const int b = rb >> 5;
  const int stile = rb & 31;
  const float* X = (t == 0) ? Xq : (t == 1) ? Xk : Xv;
  const float* W = (t == 0) ? Wq : (t == 1) ? Wk : Wv;

  const int tid = threadIdx.x;
  const int wv = tid >> 6;
  const int lane = tid & 63;
  const int j = lane & 15;
  const int g = lane >> 4;

  f32x4 acc[4];
#pragma unroll
  for (int i = 0; i < 4; ++i) acc[i] = {0.f, 0.f, 0.f, 0.f};

  const size_t xrow0 = (size_t)b * 2048 + (size_t)stile * 64;

  for (int kc = 0; kc < 768; kc += 64) {
#pragma unroll
    for (int p = 0; p < 4; ++p) {
      int lin = p * 256 + tid;   // 0..1023
      int row = lin >> 4;        // 0..63
      int seg = lin & 15;        // 16 float4 per row
      float4 xv = *(const float4*)(X + (xrow0 + row) * 768 + kc + seg * 4);
      us4 px; px.x = f2bf(xv.x); px.y = f2bf(xv.y); px.z = f2bf(xv.z); px.w = f2bf(xv.w);
      *(us4*)&xs[row][seg * 4] = px;
      float4 wv4 = *(const float4*)(W + (size_t)row * 768 + kc + seg * 4);
      us4 pw; pw.x = f2bf(wv4.x); pw.y = f2bf(wv4.y); pw.z = f2bf(wv4.z); pw.w = f2bf(wv4.w);
      *(us4*)&ws[row][seg * 4] = pw;
    }
    __syncthreads();
    s16x8 a0 = *(const s16x8*)&xs[wv * 16 + j][g * 8];
    s16x8 a1 = *(const s16x8*)&xs[wv * 16 + j][32 + g * 8];
#pragma unroll
    for (int ct = 0; ct < 4; ++ct) {
      s16x8 b0 = *(const s16x8*)&ws[ct * 16 + j][g * 8];
      s16x8 b1 = *(const s16x8*)&ws[ct * 16 + j][32 + g * 8];
      acc[ct] = MFMA16(a0, b0, acc[ct]);
      acc[ct] = MFMA16(a1, b1, acc[ct]);
    }
    __syncthreads();
  }

  if (t == 0) {
    unsigned short* out = q_out + (xrow0 + (size_t)wv * 16) * 64;
#pragma unroll
    for (int ct = 0; ct < 4; ++ct)
#pragma unroll
      for (int r = 0; r < 4; ++r)
        out[(g * 4 + r) * 64 + ct * 16 + j] = f2bf(acc[ct][r] * 0.125f);  // q pre-scale!
  } else {
    unsigned short* fb = &xs[0][0];  // 4096-short linear scratch (xs is free now)
    if (t == 1) {
      // K: thread holds K[row=stile*64+wv*16+g*4+r][d=ct*16+j]
      // frag addr16 = wv*1024 + (ct>=2)*512 + ((ct&1)*2+(j>>3))*128 + (g*4+r)*8 + (j&7)
#pragma unroll
      for (int ct = 0; ct < 4; ++ct) {
        int base16 = wv * 1024 + ((ct >= 2) ? 512 : 0) + (((ct & 1) * 2 + (j >> 3)) * 128) + (j & 7);
#pragma unroll
        for (int r = 0; r < 4; ++r)
          fb[base16 + (g * 4 + r) * 8] = f2bf(acc[ct][r]);
      }
    } else {
      // V: thread holds V[s=stile*64+wv*16+g*4+r][d=ct*16+j]
      // frag addr16 = ct*1024 + (wv>=2)*512 + (((wv&1)*2+(g>>1))*16 + j)*8 + (g&1)*4 + r
#pragma unroll
      for (int ct = 0; ct < 4; ++ct) {
        us4 pk;
        pk.x = f2bf(acc[ct][0]); pk.y = f2bf(acc[ct][1]);
        pk.z = f2bf(acc[ct][2]); pk.w = f2bf(acc[ct][3]);
        *(us4*)&fb[ct * 1024 + ((wv >= 2) ? 512 : 0) +
                   (((wv & 1) * 2 + (g >> 1)) * 16 + j) * 8 + (g & 1) * 4] = pk;
      }
    }
    __syncthreads();
    unsigned short* gb = (t == 1) ? kf_out + ((size_t)b * 128 + stile * 4) * 1024
                                  : vf_out + ((size_t)b * 32 + stile) * 4096;
#pragma unroll
    for (int p2 = 0; p2 < 2; ++p2) {
      int idx = p2 * 2048 + tid * 8;
      *(s16x8*)(gb + idx) = *(const s16x8*)&fb[idx];
    }
  }
}

// ---------------------------------------------------------------------------
// Flash attention, in-block split-K, frag-major K/V (all hot loads are
// lane-contiguous 1KB wave loads). grid = 1024 (XCD-swizzled), 4 waves/block,
// block owns 16 q-rows, wave wv sweeps KV chunk [wv*512, wv*512+512) in 8
// iterations of KT=64. V frags prefetched before softmax; defer-max skip
// (THR=6) avoids the O-rescale on most iterations. Partials merged via LDS.
// ---------------------------------------------------------------------------
__global__ __launch_bounds__(256, 4) void attn_kernel(
    const unsigned short* __restrict__ qg,  // [8][2048][64] (pre-scaled)
    const unsigned short* __restrict__ kf,  // frag-major
    const unsigned short* __restrict__ vf,  // frag-major
    float* __restrict__ out)                // [8][2048][64] f32
{
  __shared__ __align__(16) unsigned short p_lds[4][16][72];
  __shared__ __align__(16) float comb[4][16][68];
  __shared__ float mls[4][16];
  __shared__ float lls[4][16];

  const int tid = threadIdx.x;
  const int wv = tid >> 6;
  const int lane = tid & 63;
  const int j = lane & 15;
  const int g = lane >> 4;

  const int bid0 = blockIdx.x;
  const int bid = (bid0 & 7) * 128 + (bid0 >> 3);  // bijective XCD swizzle (1024 = 8*128)
  const int b = bid >> 7;
  const int qtile = bid & 127;
  const int qbase = qtile * 16;

  const unsigned short* qp = qg + (((size_t)b * 2048) + qbase) * 64;
  s16x8 q0 = *(const s16x8*)(qp + j * 64 + g * 8);
  s16x8 q1 = *(const s16x8*)(qp + j * 64 + 32 + g * 8);

  f32x4 o[4];
#pragma unroll
  for (int i = 0; i < 4; ++i) o[i] = {0.f, 0.f, 0.f, 0.f};
  float m = -1e30f, l = 0.f;

  const int kv0 = wv * 512;  // this wave's KV chunk
  const unsigned short* kfb = kf + ((size_t)b * 128 + (kv0 >> 4)) * 1024 + lane * 8;
  const unsigned short* vfb = vf + ((size_t)b * 32 + (kv0 >> 6)) * 4096 + lane * 8;

  for (int kt = 0; kt < 8; ++kt) {
    const unsigned short* kc_ = kfb + kt * 4096;
    // all-contiguous K frag loads (1KB per wave-instr)
    s16x8 ka[4], kb2[4];
#pragma unroll
    for (int ct = 0; ct < 4; ++ct) {
      ka[ct] = *(const s16x8*)(kc_ + ct * 1024);
      kb2[ct] = *(const s16x8*)(kc_ + ct * 1024 + 512);
    }
    f32x4 st[4];
#pragma unroll
    for (int ct = 0; ct < 4; ++ct) {
      f32x4 z = {0.f, 0.f, 0.f, 0.f};
      z = MFMA16(ka[ct], q0, z);
      z = MFMA16(kb2[ct], q1, z);
      st[ct] = z;  // st[ct][r] = S[q=j][k = kv0+kt*64 + ct*16 + g*4 + r]
    }
    // prefetch V frags (independent of softmax) — hides under the VALU chain
    const unsigned short* vc_ = vfb + kt * 4096;
    s16x8 va[4], vb2[4];
#pragma unroll
    for (int dt = 0; dt < 4; ++dt) {
      va[dt] = *(const s16x8*)(vc_ + dt * 1024);
      vb2[dt] = *(const s16x8*)(vc_ + dt * 1024 + 512);
    }
    // row max: in-lane + 2 shfl (lanes j, j+16, j+32, j+48 share q-row j)
    float cmax = -1e30f;
#pragma unroll
    for (int ct = 0; ct < 4; ++ct)
#pragma unroll
      for (int r = 0; r < 4; ++r) cmax = fmaxf(cmax, st[ct][r]);
    cmax = fmaxf(cmax, __shfl_xor(cmax, 16));
    cmax = fmaxf(cmax, __shfl_xor(cmax, 32));
    // defer-max: skip rescale while tile max stays within THR of running max
    if (!__all(cmax <= m + 6.0f)) {
      const float mnew = fmaxf(m, cmax);
      const float alpha = __expf(m - mnew);
      m = mnew;
      l *= alpha;
#pragma unroll
      for (int r = 0; r < 4; ++r) {
        float a_r = __shfl(alpha, g * 4 + r);
#pragma unroll
        for (int dt = 0; dt < 4; ++dt) o[dt][r] *= a_r;
      }
    }
    float rs = 0.f;
#pragma unroll
    for (int ct = 0; ct < 4; ++ct) {
      float p0 = __expf(st[ct][0] - m);
      float p1 = __expf(st[ct][1] - m);
      float p2 = __expf(st[ct][2] - m);
      float p3 = __expf(st[ct][3] - m);
      rs += (p0 + p1) + (p2 + p3);
      us4 pk; pk.x = f2bf(p0); pk.y = f2bf(p1); pk.z = f2bf(p2); pk.w = f2bf(p3);
      *(us4*)&p_lds[wv][j][ct * 16 + g * 4] = pk;  // P[q=j][k-local]
    }
    rs += __shfl_xor(rs, 16);
    rs += __shfl_xor(rs, 32);
    l += rs;
    // PV: A = P from LDS (row q = lane&15), B = V frags (contiguous)
    s16x8 pa0 = *(const s16x8*)&p_lds[wv][j][g * 8];
    s16x8 pa1 = *(const s16x8*)&p_lds[wv][j][32 + g * 8];
#pragma unroll
    for (int dt = 0; dt < 4; ++dt) {
      o[dt] = MFMA16(pa0, va[dt], o[dt]);
      o[dt] = MFMA16(pa1, vb2[dt], o[dt]);
    }
  }

  // ---- write partials to LDS: o rows q = g*4+r, cols d = dt*16+j ----
#pragma unroll
  for (int dt = 0; dt < 4; ++dt)
#pragma unroll
    for (int r = 0; r < 4; ++r)
      comb[wv][g * 4 + r][dt * 16 + j] = o[dt][r];
  if (g == 0) { mls[wv][j] = m; lls[wv][j] = l; }
  __syncthreads();

  // ---- combine: wave wv merges rows wv*4 .. wv*4+3; lane = d index ----
#pragma unroll
  for (int rr = 0; rr < 4; ++rr) {
    const int row = wv * 4 + rr;
    float m0 = mls[0][row], m1 = mls[1][row], m2 = mls[2][row], m3 = mls[3][row];
    float M = fmaxf(fmaxf(m0, m1), fmaxf(m2, m3));
    float w0 = __expf(m0 - M), w1 = __expf(m1 - M);
    float w2 = __expf(m2 - M), w3 = __expf(m3 - M);
    float acc = comb[0][row][lane] * w0 + comb[1][row][lane] * w1 +
                comb[2][row][lane] * w2 + comb[3][row][lane] * w3;
    float lt = lls[0][row] * w0 + lls[1][row] * w1 +
               lls[2][row] * w2 + lls[3][row] * w3;
    out[(((size_t)b * 2048) + qbase + row) * 64 + lane] = acc / lt;
  }
}

extern "C" void kernel_launch(void* const* d_in, const int* in_sizes, int n_in,
                              void* d_out, int out_size, void* d_ws, size_t ws_size,
                              hipStream_t stream) {
  const float* query = (const float*)d_in[0];
  const float* key_  = (const float*)d_in[1];
  const float* value = (const float*)d_in[2];
  const float* Wq = (const float*)d_in[3];
  const float* Wk = (const float*)d_in[4];
  const float* Wv = (const float*)d_in[5];

  unsigned short* qb = (unsigned short*)d_ws;       // 1M elems (row-major q)
  unsigned short* kfb = qb + 1048576u;              // 1M elems (frag-major K)
  unsigned short* vfb = qb + 2u * 1048576u;         // 1M elems (frag-major V)
  float* outp = (float*)d_out;

  hipLaunchKernelGGL(proj_kernel, dim3(768), dim3(256), 0, stream,
                     query, key_, value, Wq, Wk, Wv, qb, kfb, vfb);
  hipLaunchKernelGGL(attn_kernel, dim3(1024), dim3(256), 0, stream,
                     qb, kfb, vfb, outp);
}